// Round 6
// baseline (23.971 us; speedup 1.0000x reference)
//
#include <hip/hip_runtime.h>

#define NBATCH 1024
#define NELEC  64
#define NBAS   256
#define NORB   128
#define NROWS  (NBATCH * NELEC)
#define RPB    8    // electron-rows per block

typedef float f32x2 __attribute__((ext_vector_type(2)));

static __device__ __forceinline__ f32x2 pfma(f32x2 a, f32x2 b, f32x2 c) {
    return __builtin_elementwise_fma(a, b, c);   // -> v_pk_fma_f32 on gfx90a+
}

// canonical gfx9 wave64 inclusive prefix scan — 6 dependent VALU adds (DPP)
__device__ __forceinline__ float wave_scan_incl(float x) {
    int t;
    t = __builtin_amdgcn_update_dpp(0, __float_as_int(x), 0x111, 0xf, 0xf, false); // row_shr:1
    x += __int_as_float(t);
    t = __builtin_amdgcn_update_dpp(0, __float_as_int(x), 0x112, 0xf, 0xf, false); // row_shr:2
    x += __int_as_float(t);
    t = __builtin_amdgcn_update_dpp(0, __float_as_int(x), 0x114, 0xf, 0xf, false); // row_shr:4
    x += __int_as_float(t);
    t = __builtin_amdgcn_update_dpp(0, __float_as_int(x), 0x118, 0xf, 0xf, false); // row_shr:8
    x += __int_as_float(t);
    t = __builtin_amdgcn_update_dpp(0, __float_as_int(x), 0x142, 0xa, 0xf, false); // row_bcast:15
    x += __int_as_float(t);
    t = __builtin_amdgcn_update_dpp(0, __float_as_int(x), 0x143, 0xc, 0xf, false); // row_bcast:31
    x += __int_as_float(t);
    return x;
}

__global__ __launch_bounds__(256, 8) void ao_kernel(
    const float* __restrict__ inp,            // [NROWS, 3]
    const float* __restrict__ atom_coords,    // [16, 3]
    const float* __restrict__ bas_exp,        // [NBAS]
    const float* __restrict__ bas_coeffs,     // [NBAS]
    const float* __restrict__ norm_cst,       // [NBAS]
    const int*   __restrict__ bas_l,          // [NBAS]
    const int*   __restrict__ bas_m,          // [NBAS]
    const int*   __restrict__ bas_atom_index, // [NBAS]
    const int*   __restrict__ index_ctr,      // [NBAS] sorted
    float* __restrict__ out)                  // [NROWS, NORB]
{
    __shared__ __align__(16) float s_vals[RPB][NBAS];   // 8 KB; vals then prefix in-place
    __shared__ int s_start[NORB + 1];

    const int tid  = threadIdx.x;
    const int row0 = blockIdx.x * RPB;

    // ---- per-thread basis params: coalesced, register-resident ----
    float ex = bas_exp[tid];
    float cc = norm_cst[tid] * bas_coeffs[tid];
    int   l  = bas_l[tid];
    int   m  = bas_m[tid];
    int   ai = bas_atom_index[tid];
    float cx = atom_coords[ai*3+0], cy = atom_coords[ai*3+1], cz = atom_coords[ai*3+2];

    // start[] without binsearch/barrier: thread j fills o in (idx[j-1], idx[j]]
    int ic   = index_ctr[tid];
    int prev = (tid == 0) ? -1 : index_ctr[tid - 1];
    for (int o = prev + 1; o <= ic; ++o) s_start[o] = tid;
    if (tid == NBAS - 1)
        for (int o = ic + 1; o <= NORB; ++o) s_start[o] = NBAS;

    // fold spherical constant + cc into bilinear: P = (a.[x,y,z,1])(b.[x,y,z,1]) + c9*r2
    const float C0 = 0.2820948f, C1 = 0.4886025f, C2XY = 1.0925484f,
                C2Z2 = 0.31539156f, C2D = 0.5462742f;
    float a0=0.f,a1=0.f,a2=0.f,a3=0.f, b0=0.f,b1=0.f,b2=0.f,b3=0.f, c9=0.f;
    if (l == 0)            { a3 = cc*C0; b3 = 1.f; }
    else if (l == 1) {
        float s = cc*C1; b3 = 1.f;
        if      (m == -1) a1 = s;
        else if (m ==  0) a2 = s;
        else              a0 = s;
    } else {
        if      (m == -2) { a0 = cc*C2XY; b1 = 1.f; }                       // xy
        else if (m == -1) { a1 = cc*C2XY; b2 = 1.f; }                       // yz
        else if (m ==  0) { float s = cc*3.f*C2Z2; a2 = s; b2 = 1.f; c9 = -s/3.f; } // zz-r2/3
        else if (m ==  1) { a2 = cc*C2XY; b0 = 1.f; }                       // zx
        else              { float s = cc*C2D; a0 = s; a1 = s; b0 = 1.f; b1 = -1.f; } // (x+y)(x-y)
    }
    const float nex = -ex * 1.4426950408889634f;  // fold log2(e) for v_exp_f32

    const f32x2 vcx = {cx,cx}, vcy = {cy,cy}, vcz = {cz,cz};
    const f32x2 va0 = {a0,a0}, va1 = {a1,a1}, va2 = {a2,a2}, va3 = {a3,a3};
    const f32x2 vb0 = {b0,b0}, vb1 = {b1,b1}, vb2 = {b2,b2}, vb3 = {b3,b3};
    const f32x2 vc9 = {c9,c9}, vnx = {nex,nex};

    // ---- phase 1: evaluate basis `tid` for RPB rows, 2 rows per packed iter ----
    #pragma unroll
    for (int r = 0; r < RPB; r += 2) {
        const float* p0 = &inp[(size_t)(row0 + r) * 3];       // wave-uniform loads
        const float* p1 = &inp[(size_t)(row0 + r + 1) * 3];
        f32x2 px = {p0[0], p1[0]}, py = {p0[1], p1[1]}, pz = {p0[2], p1[2]};
        f32x2 x = px - vcx, y = py - vcy, z = pz - vcz;
        f32x2 r2 = pfma(x, x, pfma(y, y, z * z));
        f32x2 A  = pfma(va0, x, pfma(va1, y, pfma(va2, z, va3)));
        f32x2 B  = pfma(vb0, x, pfma(vb1, y, pfma(vb2, z, vb3)));
        f32x2 P  = pfma(vc9, r2, A * B);
        f32x2 t  = vnx * r2;
        f32x2 E  = { __builtin_exp2f(t.x), __builtin_exp2f(t.y) };
        f32x2 v  = E * P;
        s_vals[r    ][tid] = v.x;
        s_vals[r + 1][tid] = v.y;
    }
    __syncthreads();   // the ONLY barrier

    // ---- phase 2: wave w owns rows 2w, 2w+1 (no more barriers) ----
    const int w = tid >> 6, ln = tid & 63;
    #pragma unroll
    for (int r = 0; r < 2; ++r) {
        const int row = 2*w + r;
        float4 v = *reinterpret_cast<const float4*>(&s_vals[row][ln << 2]);
        float e0 = v.x;
        float e1 = e0 + v.y;
        float e2 = e1 + v.z;
        float e3 = e2 + v.w;
        float s    = wave_scan_incl(e3);
        float excl = s - e3;
        *reinterpret_cast<float4*>(&s_vals[row][ln << 2]) =
            make_float4(e0 + excl, e1 + excl, e2 + excl, e3 + excl);
    }

    // ---- phase 3: boundary diffs; lanes 0-31 -> row 2w, lanes 32-63 -> row 2w+1 ----
    {
        const int row = 2*w + (ln >> 5);          // block-local row
        const int q   = (ln & 31) << 2;
        int st[5];
        #pragma unroll
        for (int k = 0; k < 5; ++k) st[k] = s_start[q + k];
        float p[5];
        #pragma unroll
        for (int k = 0; k < 5; ++k) {
            int idx = st[k] - 1;
            float v = s_vals[row][idx < 0 ? 0 : idx];
            p[k] = (st[k] > 0) ? v : 0.0f;
        }
        float4 o4 = make_float4(p[1]-p[0], p[2]-p[1], p[3]-p[2], p[4]-p[3]);
        *reinterpret_cast<float4*>(&out[(size_t)(row0 + row) * NORB + q]) = o4;  // global row!
    }
}

extern "C" void kernel_launch(void* const* d_in, const int* in_sizes, int n_in,
                              void* d_out, int out_size, void* d_ws, size_t ws_size,
                              hipStream_t stream) {
    const float* inp   = (const float*)d_in[0];
    const float* atomc = (const float*)d_in[1];
    const float* bexp  = (const float*)d_in[2];
    const float* bcoef = (const float*)d_in[3];
    const float* bnorm = (const float*)d_in[4];
    // d_in[5] = bas_n (float) — redundant with bas_l, unused
    const int* bl   = (const int*)d_in[6];
    const int* bm   = (const int*)d_in[7];
    const int* bai  = (const int*)d_in[8];
    const int* ictr = (const int*)d_in[9];
    float* out = (float*)d_out;

    hipLaunchKernelGGL(ao_kernel, dim3(NROWS / RPB), dim3(256), 0, stream,
                       inp, atomc, bexp, bcoef, bnorm, bl, bm, bai, ictr, out);
}

// Round 7
// 21.136 us; speedup vs baseline: 1.1341x; 1.1341x over previous
//
#include <hip/hip_runtime.h>

#define NBAS  256
#define NORB  128
#define NROWS 65536
#define WPB   4                      // waves per block
#define RPW   4                      // rows per wave
#define ROWS_PER_BLOCK (WPB * RPW)   // 16

// canonical gfx9 wave64 inclusive prefix scan — 6 dependent VALU adds (DPP),
// HW-validated rounds 3/5 (absmax 9.8e-4)
__device__ __forceinline__ float wave_scan_incl(float x) {
    int t;
    t = __builtin_amdgcn_update_dpp(0, __float_as_int(x), 0x111, 0xf, 0xf, false); // row_shr:1
    x += __int_as_float(t);
    t = __builtin_amdgcn_update_dpp(0, __float_as_int(x), 0x112, 0xf, 0xf, false); // row_shr:2
    x += __int_as_float(t);
    t = __builtin_amdgcn_update_dpp(0, __float_as_int(x), 0x114, 0xf, 0xf, false); // row_shr:4
    x += __int_as_float(t);
    t = __builtin_amdgcn_update_dpp(0, __float_as_int(x), 0x118, 0xf, 0xf, false); // row_shr:8
    x += __int_as_float(t);
    t = __builtin_amdgcn_update_dpp(0, __float_as_int(x), 0x142, 0xa, 0xf, false); // row_bcast:15
    x += __int_as_float(t);
    t = __builtin_amdgcn_update_dpp(0, __float_as_int(x), 0x143, 0xc, 0xf, false); // row_bcast:31
    x += __int_as_float(t);
    return x;
}

__global__ __launch_bounds__(256, 6) void ao_kernel(
    const float* __restrict__ inp,            // [NROWS, 3]
    const float* __restrict__ atom_coords,    // [16, 3]
    const float* __restrict__ bas_exp,        // [NBAS]
    const float* __restrict__ bas_coeffs,     // [NBAS]
    const float* __restrict__ norm_cst,       // [NBAS]
    const int*   __restrict__ bas_l,          // [NBAS]
    const int*   __restrict__ bas_m,          // [NBAS]
    const int*   __restrict__ bas_atom_index, // [NBAS]
    const int*   __restrict__ index_ctr,      // [NBAS] sorted
    float* __restrict__ out)                  // [NROWS, NORB]
{
    __shared__ __align__(16) float s_buf[WPB][RPW][NBAS];  // wave-private row buffers, 16 KB
    __shared__ int s_start[NORB + 1];

    const int tid = threadIdx.x;
    const int w   = tid >> 6, ln = tid & 63;

    // ---- segment starts: thread j fills o in (idx[j-1], idx[j]] ----
    {
        int ic   = index_ctr[tid];
        int prev = (tid == 0) ? -1 : index_ctr[tid - 1];
        for (int o = prev + 1; o <= ic; ++o) s_start[o] = tid;
        if (tid == NBAS - 1)
            for (int o = ic + 1; o <= NORB; ++o) s_start[o] = NBAS;
    }

    // ---- per-lane params: bases ln+64j all have shell (ln mod 16) -> same (l,m) ----
    const int l = bas_l[ln], m = bas_m[ln];
    float nex[4], lcc[4], cx[4], cy[4], cz[4];
    #pragma unroll
    for (int j = 0; j < 4; ++j) {
        int b = ln + 64 * j;
        nex[j] = -bas_exp[b] * 1.4426950408889634f;          // -alpha*log2(e)
        lcc[j] = __log2f(norm_cst[b] * bas_coeffs[b]);       // cc>0 always -> fold into exp2
        int ai = bas_atom_index[b];
        cx[j] = atom_coords[ai*3+0];
        cy[j] = atom_coords[ai*3+1];
        cz[j] = atom_coords[ai*3+2];
    }
    // bilinear coefs shared across the lane's 4 bases; spherical const folded into a
    const float C0 = 0.2820948f, C1 = 0.4886025f, C2XY = 1.0925484f,
                C2Z2 = 0.31539156f, C2D = 0.5462742f;
    float a0=0.f,a1=0.f,a2=0.f,a3=0.f, b0=0.f,b1=0.f,b2=0.f,b3=0.f, c9=0.f;
    if (l == 0)            { a3 = C0; b3 = 1.f; }
    else if (l == 1) {
        b3 = 1.f;
        if      (m == -1) a1 = C1;
        else if (m ==  0) a2 = C1;
        else              a0 = C1;
    } else {
        if      (m == -2) { a0 = C2XY; b1 = 1.f; }                      // xy
        else if (m == -1) { a1 = C2XY; b2 = 1.f; }                      // yz
        else if (m ==  0) { a2 = 3.f*C2Z2; b2 = 1.f; c9 = -C2Z2; }      // 3z^2 - r^2
        else if (m ==  1) { a2 = C2XY; b0 = 1.f; }                      // zx
        else              { a0 = C2D; a1 = C2D; b0 = 1.f; b1 = -1.f; }  // (x+y)(x-y)
    }

    __syncthreads();   // the ONLY barrier — at block start; waves decouple after this
    const int st0 = s_start[2*ln], st1 = s_start[2*ln+1], st2 = s_start[2*ln+2];

    const int rowbase = __builtin_amdgcn_readfirstlane(
        (int)blockIdx.x * ROWS_PER_BLOCK + w * RPW);
    float* bufw = &s_buf[w][0][0];

    // ---- loop 1: evaluate 4 bases/lane for RPW rows (independent, deep ILP) ----
    #pragma unroll
    for (int r = 0; r < RPW; ++r) {
        const int row = rowbase + r;
        float px = inp[row*3+0], py = inp[row*3+1], pz = inp[row*3+2]; // wave-uniform
        float* buf = bufw + r * NBAS;
        #pragma unroll
        for (int j = 0; j < 4; ++j) {
            float x = px - cx[j], y = py - cy[j], z = pz - cz[j];
            float r2 = fmaf(x, x, fmaf(y, y, z * z));
            float A  = fmaf(a0, x, fmaf(a1, y, fmaf(a2, z, a3)));
            float Bv = fmaf(b0, x, fmaf(b1, y, fmaf(b2, z, b3)));
            float P  = fmaf(c9, r2, A * Bv);
            float E  = __builtin_exp2f(fmaf(nex[j], r2, lcc[j]));
            buf[ln + 64*j] = E * P;   // basis index ln+64j -> scan order preserved
        }
    }

    // ---- loop 2: per-row prefix scan in-place (intra-wave lgkmcnt ordering) ----
    #pragma unroll
    for (int r = 0; r < RPW; ++r) {
        float* buf = bufw + r * NBAS;
        float4 v = *reinterpret_cast<const float4*>(&buf[ln << 2]);
        float e0 = v.x;
        float e1 = e0 + v.y;
        float e2 = e1 + v.z;
        float e3 = e2 + v.w;
        float s    = wave_scan_incl(e3);
        float excl = s - e3;
        *reinterpret_cast<float4*>(&buf[ln << 2]) =
            make_float4(e0 + excl, e1 + excl, e2 + excl, e3 + excl);
    }

    // ---- loop 3: boundary diffs, 2 orbitals/lane/row, coalesced float2 stores ----
    #pragma unroll
    for (int r = 0; r < RPW; ++r) {
        const float* buf = bufw + r * NBAS;
        float p0 = (st0 > 0) ? buf[st0 - 1] : 0.f;
        float p1 = (st1 > 0) ? buf[st1 - 1] : 0.f;
        float p2 = (st2 > 0) ? buf[st2 - 1] : 0.f;
        const int row = rowbase + r;
        *reinterpret_cast<float2*>(&out[(size_t)row * NORB + 2*ln]) =
            make_float2(p1 - p0, p2 - p1);
    }
}

extern "C" void kernel_launch(void* const* d_in, const int* in_sizes, int n_in,
                              void* d_out, int out_size, void* d_ws, size_t ws_size,
                              hipStream_t stream) {
    const float* inp   = (const float*)d_in[0];
    const float* atomc = (const float*)d_in[1];
    const float* bexp  = (const float*)d_in[2];
    const float* bcoef = (const float*)d_in[3];
    const float* bnorm = (const float*)d_in[4];
    // d_in[5] = bas_n (float) — redundant with bas_l, unused
    const int* bl   = (const int*)d_in[6];
    const int* bm   = (const int*)d_in[7];
    const int* bai  = (const int*)d_in[8];
    const int* ictr = (const int*)d_in[9];
    float* out = (float*)d_out;

    hipLaunchKernelGGL(ao_kernel, dim3(NROWS / ROWS_PER_BLOCK), dim3(256), 0, stream,
                       inp, atomc, bexp, bcoef, bnorm, bl, bm, bai, ictr, out);
}